// Round 1
// baseline (2038.011 us; speedup 1.0000x reference)
//
#include <hip/hip_runtime.h>
#include <math.h>

#define BB   2
#define NN   32768
#define DIN  768
#define DD   512
#define PP   16
#define CC   2
#define MTOT (BB*NN)      // 65536 rows per side
#define NCHUNK 64         // attended partial chunks
#define SCALE_INV_SQRT_D 0.04419417382415922f  // 1/sqrt(512)

// ---------- block reduce (256 threads = 4 waves) ----------
__device__ __forceinline__ float block_reduce_sum_256(float v, float* sred) {
  #pragma unroll
  for (int off = 32; off; off >>= 1) v += __shfl_down(v, off);
  const int lane = threadIdx.x & 63, w = threadIdx.x >> 6;
  if (lane == 0) sred[w] = v;
  __syncthreads();
  float r = sred[0] + sred[1] + sred[2] + sred[3];
  __syncthreads();
  return r;
}

// ---------- normalize prototypes: grid PP, block 256 ----------
__global__ __launch_bounds__(256) void proto_norm_kernel(
    const float* __restrict__ prot, float* __restrict__ pn) {
  __shared__ float sred[4];
  const int p = blockIdx.x, t = threadIdx.x;
  float2 v = *(const float2*)&prot[p*DD + 2*t];
  float ss = block_reduce_sum_256(v.x*v.x + v.y*v.y, sred);
  float sc = 1.f / fmaxf(sqrtf(ss), 1e-12f);
  *(float2*)&pn[p*DD + 2*t] = make_float2(v.x*sc, v.y*sc);
}

// ---------- fp32 GEMM: proj[m][n] = X[m][:]·W[:][n] + b[n] ----------
// grid (DD/64, MTOT/64), block 256. 64x64 tile, BK=16, 4x4 per thread.
__global__ __launch_bounds__(256) void gemm_proj_kernel(
    const float* __restrict__ X, const float* __restrict__ Wm,
    const float* __restrict__ bias, float* __restrict__ outp) {
  __shared__ float As[16][64];
  __shared__ float Bs[16][64];
  const int t  = threadIdx.x;
  const int tx = t & 15, ty = t >> 4;
  const int m0 = blockIdx.y * 64, n0 = blockIdx.x * 64;
  const int am = t >> 2, ak = (t & 3) * 4;   // A-load: row am, 4 k's
  const int bk = t >> 4, bn = (t & 15) * 4;  // B-load: row bk, 4 n's
  float acc[4][4] = {};
  for (int k0 = 0; k0 < DIN; k0 += 16) {
    float4 av = *(const float4*)&X [(size_t)(m0 + am) * DIN + k0 + ak];
    float4 bv = *(const float4*)&Wm[(size_t)(k0 + bk) * DD  + n0 + bn];
    __syncthreads();
    As[ak+0][am] = av.x; As[ak+1][am] = av.y;
    As[ak+2][am] = av.z; As[ak+3][am] = av.w;
    *(float4*)&Bs[bk][bn] = bv;
    __syncthreads();
    #pragma unroll
    for (int kk = 0; kk < 16; ++kk) {
      float4 a = *(const float4*)&As[kk][ty*4];
      float4 b = *(const float4*)&Bs[kk][tx*4];
      acc[0][0] += a.x*b.x; acc[0][1] += a.x*b.y; acc[0][2] += a.x*b.z; acc[0][3] += a.x*b.w;
      acc[1][0] += a.y*b.x; acc[1][1] += a.y*b.y; acc[1][2] += a.y*b.z; acc[1][3] += a.y*b.w;
      acc[2][0] += a.z*b.x; acc[2][1] += a.z*b.y; acc[2][2] += a.z*b.z; acc[2][3] += a.z*b.w;
      acc[3][0] += a.w*b.x; acc[3][1] += a.w*b.y; acc[3][2] += a.w*b.z; acc[3][3] += a.w*b.w;
    }
  }
  const float4 bv4 = *(const float4*)&bias[n0 + tx*4];
  #pragma unroll
  for (int i = 0; i < 4; ++i) {
    float4 o;
    o.x = acc[i][0] + bv4.x; o.y = acc[i][1] + bv4.y;
    o.z = acc[i][2] + bv4.z; o.w = acc[i][3] + bv4.w;
    *(float4*)&outp[(size_t)(m0 + ty*4 + i) * DD + n0 + tx*4] = o;
  }
}

// ---------- in-place row L2 norm: grid MTOT, block 256 ----------
__global__ __launch_bounds__(256) void l2norm_rows_kernel(float* __restrict__ proj) {
  __shared__ float sred[4];
  float2* rp = (float2*)(proj + (size_t)blockIdx.x * DD);
  float2 v = rp[threadIdx.x];
  float ss = block_reduce_sum_256(v.x*v.x + v.y*v.y, sred);
  float sc = 1.f / fmaxf(sqrtf(ss), 1e-12f);
  rp[threadIdx.x] = make_float2(v.x*sc, v.y*sc);
}

// ---------- scores[b][p][n] = proj_row·pn[p] / sqrt(D) ----------
// grid 512 blocks x 4 waves, 32 rows/wave (4-row batched for LDS reuse)
__global__ __launch_bounds__(256) void scores_kernel(
    const float* __restrict__ proj, const float* __restrict__ pn,
    float* __restrict__ wbuf) {
  __shared__ float pns[PP][DD];   // 32 KB
  const int t = threadIdx.x;
  for (int i = t; i < PP*DD/4; i += 256)
    ((float4*)pns)[i] = ((const float4*)pn)[i];
  __syncthreads();
  const int wave = t >> 6, lane = t & 63;
  const int row0 = (blockIdx.x * 4 + wave) * 32;
  for (int r0 = 0; r0 < 32; r0 += 4) {
    const int row = row0 + r0;
    float v[4][8];
    #pragma unroll
    for (int r = 0; r < 4; ++r)
      #pragma unroll
      for (int k = 0; k < 8; ++k)
        v[r][k] = proj[(size_t)(row + r) * DD + lane + 64*k];
    float mine[4] = {0.f, 0.f, 0.f, 0.f};
    #pragma unroll
    for (int p = 0; p < PP; ++p) {
      float a0 = 0.f, a1 = 0.f, a2 = 0.f, a3 = 0.f;
      #pragma unroll
      for (int k = 0; k < 8; ++k) {
        float pv = pns[p][lane + 64*k];   // lane-strided: conflict-free
        a0 += v[0][k]*pv; a1 += v[1][k]*pv;
        a2 += v[2][k]*pv; a3 += v[3][k]*pv;
      }
      #pragma unroll
      for (int off = 32; off; off >>= 1) {
        a0 += __shfl_xor(a0, off); a1 += __shfl_xor(a1, off);
        a2 += __shfl_xor(a2, off); a3 += __shfl_xor(a3, off);
      }
      if (lane == p) { mine[0]=a0; mine[1]=a1; mine[2]=a2; mine[3]=a3; }
    }
    if (lane < PP) {
      #pragma unroll
      for (int r = 0; r < 4; ++r) {
        const int rw = row + r;
        const int bb = rw >> 15, nn_ = rw & (NN - 1);
        wbuf[((size_t)(bb*PP + lane))*NN + nn_] = mine[r] * SCALE_INV_SQRT_D;
      }
    }
  }
}

// ---------- softmax over n (in place): grid B*PP, block 256 ----------
__global__ __launch_bounds__(256) void softmax_kernel(float* __restrict__ wbuf) {
  __shared__ float sred[4];
  float* row = wbuf + (size_t)blockIdx.x * NN;
  const int t = threadIdx.x;
  float m = -1e30f;
  for (int i = t; i < NN; i += 256) m = fmaxf(m, row[i]);
  #pragma unroll
  for (int off = 32; off; off >>= 1) m = fmaxf(m, __shfl_xor(m, off));
  if ((t & 63) == 0) sred[t >> 6] = m;
  __syncthreads();
  m = fmaxf(fmaxf(sred[0], sred[1]), fmaxf(sred[2], sred[3]));
  __syncthreads();
  float s = 0.f;
  for (int i = t; i < NN; i += 256) { float e = expf(row[i] - m); row[i] = e; s += e; }
  s = block_reduce_sum_256(s, sred);
  const float inv = 1.f / s;
  for (int i = t; i < NN; i += 256) row[i] *= inv;
}

// ---------- attended partials (deterministic, no atomics) ----------
// grid (NCHUNK, B), block 256. part[b][chunk][p][d] = sum over 512 n.
__global__ __launch_bounds__(256) void attended_kernel(
    const float* __restrict__ proj, const float* __restrict__ wbuf,
    float* __restrict__ part) {
  __shared__ float wlds[PP][128];
  const int b = blockIdx.y, cid = blockIdx.x, t = threadIdx.x;
  const int nbase = cid * (NN / NCHUNK);   // 512 n per block
  float acc[PP][2] = {};
  for (int sub = 0; sub < NN/NCHUNK; sub += 128) {
    __syncthreads();
    { // stage 16x128 weights
      const int p = t >> 4, nn = (t & 15) * 8;
      const float* src = &wbuf[((size_t)(b*PP + p))*NN + nbase + sub + nn];
      *(float4*)&wlds[p][nn]   = *(const float4*)src;
      *(float4*)&wlds[p][nn+4] = *(const float4*)(src + 4);
    }
    __syncthreads();
    for (int nb = 0; nb < 128; nb += 8) {
      float2 pv[8];
      #pragma unroll
      for (int q = 0; q < 8; ++q)
        pv[q] = *(const float2*)&proj[(size_t)(b*NN + nbase + sub + nb + q)*DD + 2*t];
      #pragma unroll
      for (int p = 0; p < PP; ++p) {
        float4 w0 = *(const float4*)&wlds[p][nb];
        float4 w1 = *(const float4*)&wlds[p][nb+4];
        acc[p][0] += w0.x*pv[0].x + w0.y*pv[1].x + w0.z*pv[2].x + w0.w*pv[3].x
                   + w1.x*pv[4].x + w1.y*pv[5].x + w1.z*pv[6].x + w1.w*pv[7].x;
        acc[p][1] += w0.x*pv[0].y + w0.y*pv[1].y + w0.z*pv[2].y + w0.w*pv[3].y
                   + w1.x*pv[4].y + w1.y*pv[5].y + w1.z*pv[6].y + w1.w*pv[7].y;
      }
    }
  }
  #pragma unroll
  for (int p = 0; p < PP; ++p)
    *(float2*)&part[(((size_t)(b*NCHUNK + cid))*PP + p)*DD + 2*t] =
        make_float2(acc[p][0], acc[p][1]);
}

// ---------- mean over (chunk,p), L2norm -> feat[b][d]: grid B ----------
__global__ __launch_bounds__(256) void feat_kernel(
    const float* __restrict__ part, float* __restrict__ feat) {
  __shared__ float sred[4];
  const int b = blockIdx.x, t = threadIdx.x;
  float2 s = make_float2(0.f, 0.f);
  const float* base = part + (size_t)b * NCHUNK * PP * DD + 2*t;
  for (int i = 0; i < NCHUNK*PP; ++i) {
    float2 v = *(const float2*)(base + (size_t)i * DD);
    s.x += v.x; s.y += v.y;
  }
  s.x *= (1.f/PP); s.y *= (1.f/PP);
  float ss = block_reduce_sum_256(s.x*s.x + s.y*s.y, sred);
  float sc = 1.f / fmaxf(sqrtf(ss), 1e-12f);
  feat[b*DD + 2*t]     = s.x * sc;
  feat[b*DD + 2*t + 1] = s.y * sc;
}

// ---------- final head: logits, softmax, argmax, NLL ----------
__global__ void final_kernel(const float* __restrict__ featL, const float* __restrict__ featH,
                             const float* __restrict__ textL, const float* __restrict__ textH,
                             const int* __restrict__ label, float* __restrict__ out) {
  const int lane = threadIdx.x;  // 64 threads
  float l00=0,l01=0,l10=0,l11=0;
  for (int d = lane; d < DD; d += 64) {
    const float fl0 = featL[d], fl1 = featL[DD+d];
    const float fh0 = featH[d], fh1 = featH[DD+d];
    l00 += fl0*textL[d]    + fh0*textH[d];
    l01 += fl0*textL[DD+d] + fh0*textH[DD+d];
    l10 += fl1*textL[d]    + fh1*textH[d];
    l11 += fl1*textL[DD+d] + fh1*textH[DD+d];
  }
  #pragma unroll
  for (int off = 32; off; off >>= 1) {
    l00 += __shfl_xor(l00, off); l01 += __shfl_xor(l01, off);
    l10 += __shfl_xor(l10, off); l11 += __shfl_xor(l11, off);
  }
  if (lane == 0) {
    float lg[2][2] = {{l00, l01}, {l10, l11}};
    float loss = 0.f;
    for (int b = 0; b < 2; ++b) {
      const float m  = fmaxf(lg[b][0], lg[b][1]);
      const float lse = m + logf(expf(lg[b][0]-m) + expf(lg[b][1]-m));
      const float p0 = expf(lg[b][0]-lse), p1 = expf(lg[b][1]-lse);
      out[b*2+0] = p0; out[b*2+1] = p1;
      out[4+b] = (lg[b][1] > lg[b][0]) ? 1.f : 0.f;
      const int lab = label[b];
      loss += -(lg[b][lab] - lse);
    }
    out[6] = loss * 0.5f;
  }
}

extern "C" void kernel_launch(void* const* d_in, const int* in_sizes, int n_in,
                              void* d_out, int out_size, void* d_ws, size_t ws_size,
                              hipStream_t stream) {
  (void)in_sizes; (void)n_in; (void)out_size; (void)ws_size;
  const float* x_s  = (const float*)d_in[0];
  const float* x_l  = (const float*)d_in[2];
  const float* Wp   = (const float*)d_in[4];
  const float* bp   = (const float*)d_in[5];
  const float* prot = (const float*)d_in[6];
  const float* tL   = (const float*)d_in[7];
  const float* tH   = (const float*)d_in[8];
  const int*   label= (const int*)d_in[9];
  float* out = (float*)d_out;

  float* ws    = (float*)d_ws;
  float* proj  = ws;                       // 65536*512          = 33,554,432 f
  float* wbuf  = proj  + (size_t)MTOT*DD;  // 2*16*32768         =  1,048,576 f
  float* pn    = wbuf  + (size_t)BB*PP*NN; // 16*512             =      8,192 f
  float* part  = pn    + PP*DD;            // 2*64*16*512        =  1,048,576 f
  float* featL = part  + (size_t)BB*NCHUNK*PP*DD;  // 1024 f
  float* featH = featL + BB*DD;                    // 1024 f

  proto_norm_kernel<<<PP, 256, 0, stream>>>(prot, pn);

  const float* xs[2] = {x_s, x_l};
  float* fts[2] = {featL, featH};
  for (int side = 0; side < 2; ++side) {
    gemm_proj_kernel<<<dim3(DD/64, MTOT/64), 256, 0, stream>>>(xs[side], Wp, bp, proj);
    l2norm_rows_kernel<<<MTOT, 256, 0, stream>>>(proj);
    scores_kernel<<<512, 256, 0, stream>>>(proj, pn, wbuf);
    softmax_kernel<<<BB*PP, 256, 0, stream>>>(wbuf);
    attended_kernel<<<dim3(NCHUNK, BB), 256, 0, stream>>>(proj, wbuf, part);
    feat_kernel<<<BB, 256, 0, stream>>>(part, fts[side]);
  }
  final_kernel<<<1, 64, 0, stream>>>(featL, featH, tL, tH, label, out);
}

// Round 2
// 985.796 us; speedup vs baseline: 2.0674x; 2.0674x over previous
//
#include <hip/hip_runtime.h>
#include <math.h>

#define BB   2
#define NN   32768
#define DIN  768
#define DD   512
#define PP   16
#define MTOT (BB*NN)
#define NCHUNK 256
#define CHUNK  (NN/NCHUNK)   // 128
#define SCALE_INV_SQRT_D 0.04419417382415922f  // 1/sqrt(512)

typedef unsigned short u16;
typedef __attribute__((ext_vector_type(8))) short bf16x8;
typedef __attribute__((ext_vector_type(4))) float f32x4;

__device__ __forceinline__ unsigned pack2bf(float a, float b) {
  union { float f; unsigned u; } x{a}, y{b};
  unsigned ra = (x.u + 0x7FFFu + ((x.u >> 16) & 1u)) >> 16;
  unsigned rb = (y.u + 0x7FFFu + ((y.u >> 16) & 1u)) >> 16;
  return ra | (rb << 16);
}
__device__ __forceinline__ u16 f2bf(float a) {
  union { float f; unsigned u; } x{a};
  return (u16)((x.u + 0x7FFFu + ((x.u >> 16) & 1u)) >> 16);
}
__device__ __forceinline__ float bf2f(u16 u) {
  union { unsigned u; float f; } x; x.u = ((unsigned)u) << 16; return x.f;
}

__device__ __forceinline__ float block_reduce_sum_256(float v, float* sred) {
  #pragma unroll
  for (int off = 32; off; off >>= 1) v += __shfl_down(v, off);
  const int lane = threadIdx.x & 63, w = threadIdx.x >> 6;
  if (lane == 0) sred[w] = v;
  __syncthreads();
  float r = sred[0] + sred[1] + sred[2] + sred[3];
  __syncthreads();
  return r;
}

// ---------- W[768][512] fp32 -> Wt[512][768] bf16 (LDS transpose) ----------
__global__ __launch_bounds__(256) void wt_kernel(const float* __restrict__ W,
                                                 u16* __restrict__ Wt) {
  __shared__ float tile[64][65];
  const int bk = blockIdx.x, bn = blockIdx.y, t = threadIdx.x;
  #pragma unroll
  for (int i = 0; i < 16; ++i) {
    int idx = i*256 + t, kk = idx >> 6, nn = idx & 63;
    tile[kk][nn] = W[(size_t)(bk*64 + kk)*DD + bn*64 + nn];
  }
  __syncthreads();
  #pragma unroll
  for (int i = 0; i < 16; ++i) {
    int idx = i*256 + t, nn = idx >> 6, kk = idx & 63;
    Wt[(size_t)(bn*64 + nn)*DIN + bk*64 + kk] = f2bf(tile[kk][nn]);
  }
}

// ---------- normalize prototypes ----------
__global__ __launch_bounds__(256) void proto_norm_kernel(
    const float* __restrict__ prot, float* __restrict__ pn) {
  __shared__ float sred[4];
  const int p = blockIdx.x, t = threadIdx.x;
  float2 v = *(const float2*)&prot[p*DD + 2*t];
  float ss = block_reduce_sum_256(v.x*v.x + v.y*v.y, sred);
  float sc = 1.f / fmaxf(sqrtf(ss), 1e-12f);
  *(float2*)&pn[p*DD + 2*t] = make_float2(v.x*sc, v.y*sc);
}

// ---------- bf16 MFMA GEMM: proj[m][n] = bf16(X)[m][:]·Wt[n][:] + b[n] ----------
// grid 2048 (128x128 tiles), 256 threads = 4 waves (2x2), BK=64, K=768.
__global__ __launch_bounds__(256, 2) void gemm_kernel(
    const float* __restrict__ X, const u16* __restrict__ Wt,
    const float* __restrict__ bias, u16* __restrict__ proj) {
  __shared__ __align__(16) unsigned char lds[32768];  // A:0..16K, B:16K..32K
  const int t = threadIdx.x;
  const int id = blockIdx.x;
  const int swz = (id & 7) * 256 + (id >> 3);   // XCD-chunked: same-XCD neighbors share A panel
  const int bm = swz >> 2, bn = swz & 3;
  const int m0 = bm * 128, n0 = bn * 128;
  const int lane = t & 63, wid = t >> 6;
  const int wm = wid >> 1, wn = wid & 1;
  const int lr = lane & 15, lg = lane >> 4;

  const int arow = t >> 1, kh = (t & 1) * 32;
  const float* gA = X + (size_t)(m0 + arow) * DIN + kh;

  f32x4 acc[4][4] = {};

  for (int kt = 0; kt < 12; ++kt) {
    const int k0 = kt * 64;
    // ---- stage B via global_load_lds (linear LDS dest, pre-swizzled source)
    #pragma unroll
    for (int j = 0; j < 4; ++j) {
      int c = j * 256 + t;
      int nr = c >> 3, cc = c & 7;
      const u16* src = Wt + (size_t)(n0 + nr) * DIN + k0 + ((cc ^ (nr & 7)) << 3);
      __builtin_amdgcn_global_load_lds(
          (const __attribute__((address_space(1))) void*)src,
          (__attribute__((address_space(3))) void*)(lds + 16384 + j * 4096 + (t >> 6) * 1024),
          16, 0, 0);
    }
    // ---- stage A: fp32 load -> bf16 pack -> swizzled ds_write_b128
    float4 va[8];
    #pragma unroll
    for (int q = 0; q < 8; ++q) va[q] = *(const float4*)(gA + k0 + q * 4);
    #pragma unroll
    for (int q = 0; q < 4; ++q) {
      uint4 w;
      w.x = pack2bf(va[2*q].x,   va[2*q].y);
      w.y = pack2bf(va[2*q].z,   va[2*q].w);
      w.z = pack2bf(va[2*q+1].x, va[2*q+1].y);
      w.w = pack2bf(va[2*q+1].z, va[2*q+1].w);
      int chunkcol = (kh >> 3) + q;
      *(uint4*)(lds + arow * 128 + ((chunkcol ^ (arow & 7)) << 4)) = w;
    }
    __syncthreads();
    // ---- MFMA
    #pragma unroll
    for (int kk = 0; kk < 2; ++kk) {
      bf16x8 af[4], bfr[4];
      #pragma unroll
      for (int i = 0; i < 4; ++i) {
        int row = wm * 64 + i * 16 + lr;
        af[i] = *(const bf16x8*)(lds + row * 128 + (((kk * 4 + lg) ^ (row & 7)) << 4));
      }
      #pragma unroll
      for (int j = 0; j < 4; ++j) {
        int row = wn * 64 + j * 16 + lr;
        bfr[j] = *(const bf16x8*)(lds + 16384 + row * 128 + (((kk * 4 + lg) ^ (row & 7)) << 4));
      }
      #pragma unroll
      for (int i = 0; i < 4; ++i)
        #pragma unroll
        for (int j = 0; j < 4; ++j)
          acc[i][j] = __builtin_amdgcn_mfma_f32_16x16x32_bf16(af[i], bfr[j], acc[i][j], 0, 0, 0);
    }
    __syncthreads();
  }
  // ---- epilogue: +bias, bf16 store
  #pragma unroll
  for (int j = 0; j < 4; ++j) {
    int col = n0 + wn * 64 + j * 16 + lr;
    float bv = bias[col];
    #pragma unroll
    for (int i = 0; i < 4; ++i) {
      int row = m0 + wm * 64 + i * 16 + lg * 4;
      #pragma unroll
      for (int r = 0; r < 4; ++r)
        proj[(size_t)(row + r) * DD + col] = f2bf(acc[i][j][r] + bv);
    }
  }
}

// ---------- fused row-ssq + scores: wbuf[b][p][n], rnorm[row] ----------
__global__ __launch_bounds__(256) void scores_kernel(
    const u16* __restrict__ proj, const float* __restrict__ pn,
    float* __restrict__ wbuf, float* __restrict__ rnormbuf) {
  __shared__ float pns[PP][DD];   // 32 KB fp32
  const int t = threadIdx.x;
  for (int i = t; i < PP*DD/4; i += 256)
    ((float4*)pns)[i] = ((const float4*)pn)[i];
  __syncthreads();
  const int wave = t >> 6, lane = t & 63;
  const int row0 = (blockIdx.x * 4 + wave) * 32;
  for (int r0 = 0; r0 < 32; r0 += 4) {
    const int row = row0 + r0;
    float v[4][8];
    #pragma unroll
    for (int r = 0; r < 4; ++r)
      #pragma unroll
      for (int k = 0; k < 8; ++k)
        v[r][k] = bf2f(proj[(size_t)(row + r) * DD + lane + 64*k]);
    // row sum-of-squares -> rnorm
    float ss[4] = {0.f, 0.f, 0.f, 0.f};
    #pragma unroll
    for (int r = 0; r < 4; ++r)
      #pragma unroll
      for (int k = 0; k < 8; ++k) ss[r] += v[r][k] * v[r][k];
    #pragma unroll
    for (int off = 32; off; off >>= 1) {
      ss[0] += __shfl_xor(ss[0], off); ss[1] += __shfl_xor(ss[1], off);
      ss[2] += __shfl_xor(ss[2], off); ss[3] += __shfl_xor(ss[3], off);
    }
    float rn[4];
    #pragma unroll
    for (int r = 0; r < 4; ++r) rn[r] = 1.f / fmaxf(sqrtf(ss[r]), 1e-12f);
    if (lane == 0) {
      #pragma unroll
      for (int r = 0; r < 4; ++r) rnormbuf[row + r] = rn[r];
    }
    float mine[4] = {0.f, 0.f, 0.f, 0.f};
    #pragma unroll
    for (int p = 0; p < PP; ++p) {
      float a0 = 0.f, a1 = 0.f, a2 = 0.f, a3 = 0.f;
      #pragma unroll
      for (int k = 0; k < 8; ++k) {
        float pv = pns[p][lane + 64*k];
        a0 += v[0][k]*pv; a1 += v[1][k]*pv;
        a2 += v[2][k]*pv; a3 += v[3][k]*pv;
      }
      #pragma unroll
      for (int off = 32; off; off >>= 1) {
        a0 += __shfl_xor(a0, off); a1 += __shfl_xor(a1, off);
        a2 += __shfl_xor(a2, off); a3 += __shfl_xor(a3, off);
      }
      if (lane == p) { mine[0]=a0; mine[1]=a1; mine[2]=a2; mine[3]=a3; }
    }
    if (lane < PP) {
      #pragma unroll
      for (int r = 0; r < 4; ++r) {
        const int rw = row + r;
        const int bb = rw >> 15, nn_ = rw & (NN - 1);
        wbuf[((size_t)(bb*PP + lane))*NN + nn_] = mine[r] * rn[r] * SCALE_INV_SQRT_D;
      }
    }
  }
}

// ---------- softmax over n (in place): grid B*PP ----------
__global__ __launch_bounds__(256) void softmax_kernel(float* __restrict__ wbuf) {
  __shared__ float sred[4];
  float* row = wbuf + (size_t)blockIdx.x * NN;
  const int t = threadIdx.x;
  float m = -1e30f;
  for (int i = t; i < NN; i += 256) m = fmaxf(m, row[i]);
  #pragma unroll
  for (int off = 32; off; off >>= 1) m = fmaxf(m, __shfl_xor(m, off));
  if ((t & 63) == 0) sred[t >> 6] = m;
  __syncthreads();
  m = fmaxf(fmaxf(sred[0], sred[1]), fmaxf(sred[2], sred[3]));
  __syncthreads();
  float s = 0.f;
  for (int i = t; i < NN; i += 256) { float e = expf(row[i] - m); row[i] = e; s += e; }
  s = block_reduce_sum_256(s, sred);
  const float inv = 1.f / s;
  for (int i = t; i < NN; i += 256) row[i] *= inv;
}

// ---------- wsum[b][n] = (1/P)·rnorm[b][n]·Σ_p w[b][p][n] ----------
__global__ __launch_bounds__(256) void wsum_kernel(
    const float* __restrict__ wbuf, const float* __restrict__ rnormbuf,
    float* __restrict__ wsum) {
  const int gid = blockIdx.x * 256 + threadIdx.x;   // 0..MTOT-1
  const int b = gid >> 15, n = gid & (NN - 1);
  float s = 0.f;
  #pragma unroll
  for (int p = 0; p < PP; ++p) s += wbuf[((size_t)(b*PP + p))*NN + n];
  wsum[gid] = s * rnormbuf[gid] * (1.f / PP);
}

// ---------- attended partials: part[b][cid][d] = Σ_{n in chunk} wsum[n]·proj[n][d] ----------
__global__ __launch_bounds__(256) void attended_kernel(
    const u16* __restrict__ proj, const float* __restrict__ wsum,
    float* __restrict__ part) {
  __shared__ float wl[CHUNK];
  const int b = blockIdx.y, cid = blockIdx.x, t = threadIdx.x;
  const int nbase = cid * CHUNK;
  if (t < CHUNK) wl[t] = wsum[b*NN + nbase + t];
  __syncthreads();
  float a0 = 0.f, a1 = 0.f;
  const u16* pb = proj + (size_t)(b*NN + nbase) * DD + 2*t;
  #pragma unroll 8
  for (int n = 0; n < CHUNK; ++n) {
    unsigned uu = *(const unsigned*)(pb + (size_t)n * DD);
    float w = wl[n];
    a0 += w * bf2f((u16)uu);
    a1 += w * bf2f((u16)(uu >> 16));
  }
  *(float2*)&part[((size_t)(b*NCHUNK + cid))*DD + 2*t] = make_float2(a0, a1);
}

// ---------- reduce chunks + L2norm -> feat[b][d] ----------
__global__ __launch_bounds__(256) void feat_kernel(
    const float* __restrict__ part, float* __restrict__ feat) {
  __shared__ float sred[4];
  const int b = blockIdx.x, t = threadIdx.x;
  float2 s = make_float2(0.f, 0.f);
  const float* base = part + (size_t)b * NCHUNK * DD + 2*t;
  for (int c = 0; c < NCHUNK; ++c) {
    float2 v = *(const float2*)(base + (size_t)c * DD);
    s.x += v.x; s.y += v.y;
  }
  float ss = block_reduce_sum_256(s.x*s.x + s.y*s.y, sred);
  float sc = 1.f / fmaxf(sqrtf(ss), 1e-12f);
  feat[b*DD + 2*t]     = s.x * sc;
  feat[b*DD + 2*t + 1] = s.y * sc;
}

// ---------- final head ----------
__global__ void final_kernel(const float* __restrict__ featL, const float* __restrict__ featH,
                             const float* __restrict__ textL, const float* __restrict__ textH,
                             const int* __restrict__ label, float* __restrict__ out) {
  const int lane = threadIdx.x;  // 64 threads
  float l00=0,l01=0,l10=0,l11=0;
  for (int d = lane; d < DD; d += 64) {
    const float fl0 = featL[d], fl1 = featL[DD+d];
    const float fh0 = featH[d], fh1 = featH[DD+d];
    l00 += fl0*textL[d]    + fh0*textH[d];
    l01 += fl0*textL[DD+d] + fh0*textH[DD+d];
    l10 += fl1*textL[d]    + fh1*textH[d];
    l11 += fl1*textL[DD+d] + fh1*textH[DD+d];
  }
  #pragma unroll
  for (int off = 32; off; off >>= 1) {
    l00 += __shfl_xor(l00, off); l01 += __shfl_xor(l01, off);
    l10 += __shfl_xor(l10, off); l11 += __shfl_xor(l11, off);
  }
  if (lane == 0) {
    float lg[2][2] = {{l00, l01}, {l10, l11}};
    float loss = 0.f;
    for (int b = 0; b < 2; ++b) {
      const float m  = fmaxf(lg[b][0], lg[b][1]);
      const float lse = m + logf(expf(lg[b][0]-m) + expf(lg[b][1]-m));
      out[b*2+0] = expf(lg[b][0]-lse); out[b*2+1] = expf(lg[b][1]-lse);
      out[4+b] = (lg[b][1] > lg[b][0]) ? 1.f : 0.f;
      loss += -(lg[b][label[b]] - lse);
    }
    out[6] = loss * 0.5f;
  }
}

extern "C" void kernel_launch(void* const* d_in, const int* in_sizes, int n_in,
                              void* d_out, int out_size, void* d_ws, size_t ws_size,
                              hipStream_t stream) {
  (void)in_sizes; (void)n_in; (void)out_size; (void)ws_size;
  const float* x_s  = (const float*)d_in[0];
  const float* x_l  = (const float*)d_in[2];
  const float* Wp   = (const float*)d_in[4];
  const float* bp   = (const float*)d_in[5];
  const float* prot = (const float*)d_in[6];
  const float* tL   = (const float*)d_in[7];
  const float* tH   = (const float*)d_in[8];
  const int*   label= (const int*)d_in[9];
  float* out = (float*)d_out;

  unsigned char* w8 = (unsigned char*)d_ws;
  u16*   proj   = (u16*)  (w8);                 // 67,108,864 B
  float* wbuf   = (float*)(w8 + 67108864);      //  4,194,304 B
  float* pn     = (float*)(w8 + 71303168);      //     32,768 B
  u16*   Wt     = (u16*)  (w8 + 71335936);      //    786,432 B
  float* rnormb = (float*)(w8 + 72122368);      //    262,144 B
  float* wsum   = (float*)(w8 + 72384512);      //    262,144 B
  float* part   = (float*)(w8 + 72646656);      //  1,048,576 B
  float* featL  = (float*)(w8 + 73695232);      //      4,096 B
  float* featH  = (float*)(w8 + 73699328);      //      4,096 B

  wt_kernel<<<dim3(12, 8), 256, 0, stream>>>(Wp, Wt);
  proto_norm_kernel<<<PP, 256, 0, stream>>>(prot, pn);

  const float* xs[2] = {x_s, x_l};
  float* fts[2] = {featL, featH};
  for (int side = 0; side < 2; ++side) {
    gemm_kernel<<<2048, 256, 0, stream>>>(xs[side], Wt, bp, proj);
    scores_kernel<<<512, 256, 0, stream>>>(proj, pn, wbuf, rnormb);
    softmax_kernel<<<BB*PP, 256, 0, stream>>>(wbuf);
    wsum_kernel<<<MTOT/256, 256, 0, stream>>>(wbuf, rnormb, wsum);
    attended_kernel<<<dim3(NCHUNK, BB), 256, 0, stream>>>(proj, wsum, part);
    feat_kernel<<<BB, 256, 0, stream>>>(part, fts[side]);
  }
  final_kernel<<<1, 64, 0, stream>>>(featL, featH, tL, tH, label, out);
}

// Round 3
// 302.423 us; speedup vs baseline: 6.7389x; 3.2597x over previous
//
#include <hip/hip_runtime.h>
#include <math.h>

#define BB   2
#define NN   32768
#define DIN  768
#define DD   512
#define PP   16
#define MTOT (BB*NN)
#define NCHUNK 256
#define CHUNK  (NN/NCHUNK)   // 128
#define SCALE_INV_SQRT_D 0.04419417382415922f  // 1/sqrt(512)

typedef unsigned short u16;
typedef __attribute__((ext_vector_type(8))) short bf16x8;
typedef __attribute__((ext_vector_type(4))) float f32x4;

__device__ __forceinline__ unsigned pack2bf(float a, float b) {
  union { float f; unsigned u; } x{a}, y{b};
  unsigned ra = (x.u + 0x7FFFu + ((x.u >> 16) & 1u)) >> 16;
  unsigned rb = (y.u + 0x7FFFu + ((y.u >> 16) & 1u)) >> 16;
  return ra | (rb << 16);
}
__device__ __forceinline__ u16 f2bf(float a) {
  union { float f; unsigned u; } x{a};
  return (u16)((x.u + 0x7FFFu + ((x.u >> 16) & 1u)) >> 16);
}
__device__ __forceinline__ float bf2f(u16 u) {
  union { unsigned u; float f; } x; x.u = ((unsigned)u) << 16; return x.f;
}

__device__ __forceinline__ float block_reduce_sum_256(float v, float* sred) {
  #pragma unroll
  for (int off = 32; off; off >>= 1) v += __shfl_down(v, off);
  const int lane = threadIdx.x & 63, w = threadIdx.x >> 6;
  if (lane == 0) sred[w] = v;
  __syncthreads();
  float r = sred[0] + sred[1] + sred[2] + sred[3];
  __syncthreads();
  return r;
}

// ---------- W[768][512] fp32 -> Bf fragment layout: Bf[nf*24+ks][lane] = 8 bf16 ----------
// element: n = nf*16 + (lane&15), k = ks*32 + (lane>>4)*8 + j
__global__ __launch_bounds__(64) void bf_pack_kernel(const float* __restrict__ W,
                                                     uint4* __restrict__ Bf) {
  const int bid = blockIdx.x;            // nf*24 + ks, 768 blocks
  const int nf = bid / 24, ks = bid % 24;
  const int lane = threadIdx.x;
  const int n = nf*16 + (lane & 15);
  const int kb = ks*32 + (lane >> 4)*8;
  unsigned r0 = pack2bf(W[(size_t)(kb+0)*DD + n], W[(size_t)(kb+1)*DD + n]);
  unsigned r1 = pack2bf(W[(size_t)(kb+2)*DD + n], W[(size_t)(kb+3)*DD + n]);
  unsigned r2 = pack2bf(W[(size_t)(kb+4)*DD + n], W[(size_t)(kb+5)*DD + n]);
  unsigned r3 = pack2bf(W[(size_t)(kb+6)*DD + n], W[(size_t)(kb+7)*DD + n]);
  Bf[(size_t)bid*64 + lane] = make_uint4(r0, r1, r2, r3);
}

// ---------- normalize prototypes -> pn fp32 [16][512] ----------
__global__ __launch_bounds__(256) void proto_norm_kernel(
    const float* __restrict__ prot, float* __restrict__ pn) {
  __shared__ float sred[4];
  const int p = blockIdx.x, t = threadIdx.x;
  float2 v = *(const float2*)&prot[p*DD + 2*t];
  float ss = block_reduce_sum_256(v.x*v.x + v.y*v.y, sred);
  float sc = 1.f / fmaxf(sqrtf(ss), 1e-12f);
  *(float2*)&pn[p*DD + 2*t] = make_float2(v.x*sc, v.y*sc);
}

// ---------- pn -> fragment layout pnb[ks][lane], ks 0..15 ----------
__global__ __launch_bounds__(64) void pn_pack_kernel(const float* __restrict__ pn,
                                                     uint4* __restrict__ pnb) {
  const int ks = blockIdx.x, lane = threadIdx.x;
  const int p = lane & 15;
  const int kb = ks*32 + (lane >> 4)*8;
  unsigned r0 = pack2bf(pn[p*DD + kb+0], pn[p*DD + kb+1]);
  unsigned r1 = pack2bf(pn[p*DD + kb+2], pn[p*DD + kb+3]);
  unsigned r2 = pack2bf(pn[p*DD + kb+4], pn[p*DD + kb+5]);
  unsigned r3 = pack2bf(pn[p*DD + kb+6], pn[p*DD + kb+7]);
  pnb[ks*64 + lane] = make_uint4(r0, r1, r2, r3);
}

// ---------- GEMM: BM=64, BN=512 (full N), BK=64, A-only LDS dbuf, B reg-direct from L2 ----------
// grid 1024 (one 64-row slab each), 256 threads = 4 waves, wave tile 64x128.
__global__ __launch_bounds__(256, 2) void gemm_kernel(
    const float* __restrict__ X, const uint4* __restrict__ Bf,
    const float* __restrict__ bias, u16* __restrict__ proj) {
  __shared__ __align__(16) unsigned char Alds[2][8192];
  const int t = threadIdx.x, lane = t & 63, wn = t >> 6;
  const int m0 = blockIdx.x * 64;
  const int r = t >> 2, mf = r >> 4, lr = r & 15, c4 = t & 3;
  const int cl = lane & 15, cg = lane >> 4;
  const float* gA = X + (size_t)(m0 + r) * DIN + c4 * 4;
  int wslot[4];
  #pragma unroll
  for (int q = 0; q < 4; ++q)
    wslot[q] = ((mf*2 + (q>>1))*64 + ((q&1)*2 + (c4>>1))*16 + lr) * 16 + (c4&1)*8;

  f32x4 acc[4][8] = {};
  float4 va[4];
  #pragma unroll
  for (int q = 0; q < 4; ++q) va[q] = *(const float4*)(gA + q*16);
  #pragma unroll
  for (int q = 0; q < 4; ++q)
    *(uint2*)(&Alds[0][wslot[q]]) =
        make_uint2(pack2bf(va[q].x, va[q].y), pack2bf(va[q].z, va[q].w));

  for (int kt = 0; kt < 12; ++kt) {
    const int cur = kt & 1;
    if (kt < 11) {
      #pragma unroll
      for (int q = 0; q < 4; ++q) va[q] = *(const float4*)(gA + (kt+1)*64 + q*16);
    }
    bf16x8 b0[8];
    #pragma unroll
    for (int j = 0; j < 8; ++j)
      b0[j] = *(const bf16x8*)(Bf + (size_t)((wn*8 + j)*24 + kt*2) * 64 + lane);
    __syncthreads();
    bf16x8 af0[4], af1[4];
    #pragma unroll
    for (int m = 0; m < 4; ++m)
      af0[m] = *(const bf16x8*)(&Alds[cur][((m*2 + 0)*64 + lane)*16]);
    #pragma unroll
    for (int m = 0; m < 4; ++m)
      af1[m] = *(const bf16x8*)(&Alds[cur][((m*2 + 1)*64 + lane)*16]);
    #pragma unroll
    for (int j = 0; j < 8; ++j)
      #pragma unroll
      for (int m = 0; m < 4; ++m)
        acc[m][j] = __builtin_amdgcn_mfma_f32_16x16x32_bf16(af0[m], b0[j], acc[m][j], 0, 0, 0);
    bf16x8 b1[8];
    #pragma unroll
    for (int j = 0; j < 8; ++j)
      b1[j] = *(const bf16x8*)(Bf + (size_t)((wn*8 + j)*24 + kt*2 + 1) * 64 + lane);
    #pragma unroll
    for (int j = 0; j < 8; ++j)
      #pragma unroll
      for (int m = 0; m < 4; ++m)
        acc[m][j] = __builtin_amdgcn_mfma_f32_16x16x32_bf16(af1[m], b1[j], acc[m][j], 0, 0, 0);
    if (kt < 11) {
      #pragma unroll
      for (int q = 0; q < 4; ++q)
        *(uint2*)(&Alds[cur^1][wslot[q]]) =
            make_uint2(pack2bf(va[q].x, va[q].y), pack2bf(va[q].z, va[q].w));
    }
  }
  #pragma unroll
  for (int j = 0; j < 8; ++j) {
    const int col = wn*128 + j*16 + cl;
    const float bv = bias[col];
    #pragma unroll
    for (int m = 0; m < 4; ++m) {
      const size_t rowb = (size_t)(m0 + m*16 + cg*4) * DD + col;
      #pragma unroll
      for (int rr = 0; rr < 4; ++rr)
        proj[rowb + (size_t)rr*DD] = f2bf(acc[m][j][rr] + bv);
    }
  }
}

// ---------- scores via MFMA + fused ssq/rnorm: grid 512, 4 waves x 32 rows ----------
__global__ __launch_bounds__(256) void scores_kernel(
    const u16* __restrict__ proj, const uint4* __restrict__ pnb,
    float* __restrict__ wbuf, float* __restrict__ rnormbuf) {
  __shared__ float ssq_lds[4][16];
  const int t = threadIdx.x, lane = t & 63, wave = t >> 6;
  const int cl = lane & 15, cg = lane >> 4;
  bf16x8 pf[16];
  #pragma unroll
  for (int ks = 0; ks < 16; ++ks) pf[ks] = *(const bf16x8*)(pnb + ks*64 + lane);
  const int rows0 = (blockIdx.x * 4 + wave) * 32;
  #pragma unroll
  for (int rg = 0; rg < 2; ++rg) {
    const int row0 = rows0 + rg * 16;
    f32x4 sacc = {0.f, 0.f, 0.f, 0.f};
    float ssq = 0.f;
    #pragma unroll
    for (int ks = 0; ks < 16; ++ks) {
      bf16x8 af = *(const bf16x8*)(proj + (size_t)(row0 + cl)*DD + ks*32 + cg*8);
      sacc = __builtin_amdgcn_mfma_f32_16x16x32_bf16(af, pf[ks], sacc, 0, 0, 0);
      #pragma unroll
      for (int j = 0; j < 8; ++j) { float v = bf2f((u16)af[j]); ssq += v*v; }
    }
    ssq += __shfl_xor(ssq, 16);
    ssq += __shfl_xor(ssq, 32);
    if (lane < 16) {
      ssq_lds[wave][lane] = ssq;
      rnormbuf[row0 + lane] = 1.f / fmaxf(sqrtf(ssq), 1e-12f);
    }
    __syncthreads();
    float rn[4];
    #pragma unroll
    for (int rr = 0; rr < 4; ++rr)
      rn[rr] = 1.f / fmaxf(sqrtf(ssq_lds[wave][cg*4 + rr]), 1e-12f);
    __syncthreads();
    #pragma unroll
    for (int rr = 0; rr < 4; ++rr) {
      const int gr = row0 + cg*4 + rr;
      const int b = gr >> 15, n = gr & (NN - 1);
      wbuf[((size_t)(b*PP + cl))*NN + n] = sacc[rr] * rn[rr] * SCALE_INV_SQRT_D;
    }
  }
}

// ---------- per-(b,p) row max + inv-sum: grid 32 ----------
__global__ __launch_bounds__(256) void sm1_kernel(const float* __restrict__ wbuf,
                                                  float* __restrict__ Mrow,
                                                  float* __restrict__ iSrow) {
  __shared__ float sred[4];
  const int rid = blockIdx.x, t = threadIdx.x;
  const float4* row = (const float4*)(wbuf + (size_t)rid * NN);
  float m = -1e30f;
  for (int i = t; i < NN/4; i += 256) {
    float4 v = row[i];
    m = fmaxf(fmaxf(fmaxf(m, v.x), v.y), fmaxf(v.z, v.w));
  }
  #pragma unroll
  for (int off = 32; off; off >>= 1) m = fmaxf(m, __shfl_xor(m, off));
  if ((t & 63) == 0) sred[t >> 6] = m;
  __syncthreads();
  m = fmaxf(fmaxf(sred[0], sred[1]), fmaxf(sred[2], sred[3]));
  __syncthreads();
  float s = 0.f;
  for (int i = t; i < NN/4; i += 256) {
    float4 v = row[i];
    s += expf(v.x - m) + expf(v.y - m) + expf(v.z - m) + expf(v.w - m);
  }
  s = block_reduce_sum_256(s, sred);
  if (t == 0) { Mrow[rid] = m; iSrow[rid] = 1.f / s; }
}

// ---------- wsum[b][n] = (1/P)·rnorm·Σ_p exp(w-M)·iS : grid 256 ----------
__global__ __launch_bounds__(256) void wsum_kernel(
    const float* __restrict__ wbuf, const float* __restrict__ rnormbuf,
    const float* __restrict__ Mrow, const float* __restrict__ iSrow,
    float* __restrict__ wsum) {
  const int gid = blockIdx.x * 256 + threadIdx.x;
  const int b = gid >> 15, n = gid & (NN - 1);
  float s = 0.f;
  #pragma unroll
  for (int p = 0; p < PP; ++p)
    s += expf(wbuf[((size_t)(b*PP + p))*NN + n] - Mrow[b*PP + p]) * iSrow[b*PP + p];
  wsum[gid] = s * rnormbuf[gid] * (1.f / PP);
}

// ---------- attended partials: part[b][cid][d] = Σ_{n in chunk} wsum[n]·proj[n][d] ----------
__global__ __launch_bounds__(256) void attended_kernel(
    const u16* __restrict__ proj, const float* __restrict__ wsum,
    float* __restrict__ part) {
  __shared__ float wl[CHUNK];
  const int b = blockIdx.y, cid = blockIdx.x, t = threadIdx.x;
  const int nbase = cid * CHUNK;
  if (t < CHUNK) wl[t] = wsum[b*NN + nbase + t];
  __syncthreads();
  float a0 = 0.f, a1 = 0.f;
  const u16* pb = proj + (size_t)(b*NN + nbase) * DD + 2*t;
  #pragma unroll 8
  for (int n = 0; n < CHUNK; ++n) {
    unsigned uu = *(const unsigned*)(pb + (size_t)n * DD);
    float w = wl[n];
    a0 += w * bf2f((u16)uu);
    a1 += w * bf2f((u16)(uu >> 16));
  }
  *(float2*)&part[((size_t)(b*NCHUNK + cid))*DD + 2*t] = make_float2(a0, a1);
}

// ---------- reduce chunks + L2norm -> feat[b][d] ----------
__global__ __launch_bounds__(256) void feat_kernel(
    const float* __restrict__ part, float* __restrict__ feat) {
  __shared__ float sred[4];
  const int b = blockIdx.x, t = threadIdx.x;
  float2 s = make_float2(0.f, 0.f);
  const float* base = part + (size_t)b * NCHUNK * DD + 2*t;
  for (int c = 0; c < NCHUNK; ++c) {
    float2 v = *(const float2*)(base + (size_t)c * DD);
    s.x += v.x; s.y += v.y;
  }
  float ss = block_reduce_sum_256(s.x*s.x + s.y*s.y, sred);
  float sc = 1.f / fmaxf(sqrtf(ss), 1e-12f);
  feat[b*DD + 2*t]     = s.x * sc;
  feat[b*DD + 2*t + 1] = s.y * sc;
}

// ---------- final head ----------
__global__ void final_kernel(const float* __restrict__ featL, const float* __restrict__ featH,
                             const float* __restrict__ textL, const float* __restrict__ textH,
                             const int* __restrict__ label, float* __restrict__ out) {
  const int lane = threadIdx.x;  // 64 threads
  float l00=0,l01=0,l10=0,l11=0;
  for (int d = lane; d < DD; d += 64) {
    const float fl0 = featL[d], fl1 = featL[DD+d];
    const float fh0 = featH[d], fh1 = featH[DD+d];
    l00 += fl0*textL[d]    + fh0*textH[d];
    l01 += fl0*textL[DD+d] + fh0*textH[DD+d];
    l10 += fl1*textL[d]    + fh1*textH[d];
    l11 += fl1*textL[DD+d] + fh1*textH[DD+d];
  }
  #pragma unroll
  for (int off = 32; off; off >>= 1) {
    l00 += __shfl_xor(l00, off); l01 += __shfl_xor(l01, off);
    l10 += __shfl_xor(l10, off); l11 += __shfl_xor(l11, off);
  }
  if (lane == 0) {
    float lg[2][2] = {{l00, l01}, {l10, l11}};
    float loss = 0.f;
    for (int b = 0; b < 2; ++b) {
      const float m  = fmaxf(lg[b][0], lg[b][1]);
      const float lse = m + logf(expf(lg[b][0]-m) + expf(lg[b][1]-m));
      out[b*2+0] = expf(lg[b][0]-lse); out[b*2+1] = expf(lg[b][1]-lse);
      out[4+b] = (lg[b][1] > lg[b][0]) ? 1.f : 0.f;
      loss += -(lg[b][label[b]] - lse);
    }
    out[6] = loss * 0.5f;
  }
}

extern "C" void kernel_launch(void* const* d_in, const int* in_sizes, int n_in,
                              void* d_out, int out_size, void* d_ws, size_t ws_size,
                              hipStream_t stream) {
  (void)in_sizes; (void)n_in; (void)out_size; (void)ws_size;
  const float* x_s  = (const float*)d_in[0];
  const float* x_l  = (const float*)d_in[2];
  const float* Wp   = (const float*)d_in[4];
  const float* bp   = (const float*)d_in[5];
  const float* prot = (const float*)d_in[6];
  const float* tL   = (const float*)d_in[7];
  const float* tH   = (const float*)d_in[8];
  const int*   label= (const int*)d_in[9];
  float* out = (float*)d_out;

  unsigned char* w8 = (unsigned char*)d_ws;
  u16*   proj   = (u16*)  (w8);                 // 67,108,864
  float* wbuf   = (float*)(w8 + 67108864);      //  4,194,304
  float* pn     = (float*)(w8 + 71303168);      //     32,768
  uint4* Bf     = (uint4*)(w8 + 71335936);      //    786,432
  uint4* pnb    = (uint4*)(w8 + 72122368);      //     16,384
  float* rnormb = (float*)(w8 + 72138752);      //    262,144
  float* wsum   = (float*)(w8 + 72400896);      //    262,144
  float* Mrow   = (float*)(w8 + 72663040);      //        128
  float* iSrow  = (float*)(w8 + 72663168);      //        128
  float* part   = (float*)(w8 + 72663296);      //  1,048,576
  float* featL  = (float*)(w8 + 73711872);      //      4,096
  float* featH  = (float*)(w8 + 73715968);      //      4,096

  bf_pack_kernel<<<768, 64, 0, stream>>>(Wp, Bf);
  proto_norm_kernel<<<PP, 256, 0, stream>>>(prot, pn);
  pn_pack_kernel<<<16, 64, 0, stream>>>(pn, pnb);

  const float* xs[2] = {x_s, x_l};
  float* fts[2] = {featL, featH};
  for (int side = 0; side < 2; ++side) {
    gemm_kernel<<<MTOT/64, 256, 0, stream>>>(xs[side], Bf, bp, proj);
    scores_kernel<<<512, 256, 0, stream>>>(proj, pnb, wbuf, rnormb);
    sm1_kernel<<<BB*PP, 256, 0, stream>>>(wbuf, Mrow, iSrow);
    wsum_kernel<<<MTOT/256, 256, 0, stream>>>(wbuf, rnormb, Mrow, iSrow, wsum);
    attended_kernel<<<dim3(NCHUNK, BB), 256, 0, stream>>>(proj, wsum, part);
    feat_kernel<<<BB, 256, 0, stream>>>(part, fts[side]);
  }
  final_kernel<<<1, 64, 0, stream>>>(featL, featH, tL, tH, label, out);
}